// Round 4
// baseline (300.359 us; speedup 1.0000x reference)
//
#include <hip/hip_runtime.h>
#include <math.h>

// L=4096, N=16, H=16, E=64. rows = L*N = 65536. data[l][n][h][e] fp32.
// out[l][n][h][f] = exp(x.proj[h,:,f] - 0.5*||x||^2) + 1e-6, x = row*64^-0.25.
// proj = q^T D of LAPACK-convention QR(pm[h]^T), D = sign(diag(r)) (column
// scaling of q^T => convention-DEPENDENT, must reproduce geqrf signs).
// Fused single kernel: each block redoes its head's QR (registers + LDS),
// then streams 16 tiles of 256 rows with global_load_lds double-buffering.

#define AS1 __attribute__((address_space(1)))
#define AS3 __attribute__((address_space(3)))

#define BARLDS() do { asm volatile("s_waitcnt lgkmcnt(0)" ::: "memory"); \
                      __builtin_amdgcn_s_barrier();                      \
                      asm volatile("" ::: "memory"); } while (0)
#define VMCNT0() asm volatile("s_waitcnt vmcnt(0)" ::: "memory")

#if __has_builtin(__builtin_amdgcn_exp2f)
#define EXP2F(x) __builtin_amdgcn_exp2f(x)
#else
#define EXP2F(x) exp2f(x)
#endif

static __device__ __forceinline__ void gload16(const float* g, float* l) {
    __builtin_amdgcn_global_load_lds((AS1 const void*)g, (AS3 void*)l, 16, 0, 0);
}

__global__ __launch_bounds__(256) void fused_kernel(const float* __restrict__ data,
                                                    const float* __restrict__ pm,
                                                    float* __restrict__ out)
{
    // X tile: 64 groups of (4 rows x 64 floats contiguous) + 4-float pad = 260
    __shared__ float Xs[2][64 * 260];     // 2 x 66560 B (QR scratch overlays Xs[1])
    __shared__ float Ps[64 * 64];         // proj[e][f] * 64^-0.25 * log2(e)

    const int tid   = threadIdx.x;
    const int h     = blockIdx.x & 15;
    const int chunk = blockIdx.x >> 4;            // 0..15
    const size_t rowbase = (size_t)chunk * 4096;  // 16 tiles x 256 rows

    const int lane = tid & 63;
    const int wv   = tid >> 6;                    // wave id; wave w owns rows 64w..64w+63
    const float* gdat = data + (size_t)h * 64 + (size_t)(lane >> 4) * 1024 + (lane & 15) * 4;

    // ---------------- prefetch tile 0 (hides under QR) ----------------
    {
        const float* gt = gdat + rowbase * 1024;
        #pragma unroll
        for (int i = 0; i < 16; ++i) {
            const int g = wv * 16 + i;
            gload16(gt + (size_t)g * 4096, &Xs[0][g * 260]);
        }
    }

    // ---------------- per-head QR (fp64, LAPACK dlarfg signs) ----------------
    {
        double* S     = (double*)&Xs[1][0];
        double* Rs    = S;                 // 64*65 = 4160
        double* Ws    = S + 4160;          // 256
        double* colb  = S + 4416;          // 64
        double* nrmb  = S + 4480;          // 4
        double* betas = S + 4484;          // 64
        double* qcA   = S + 4548;          // 64
        double* qcB   = S + 4612;          // 64
        double* invb  = S + 4676;          // 64
        double* sgn   = S + 4740;          // 64

        const int c = tid & 63, q = tid >> 6, i0 = q * 16;
        double A[16], M[16];
        #pragma unroll
        for (int k = 0; k < 16; ++k)
            A[k] = M[k] = (double)pm[h * 4096 + c * 64 + i0 + k];  // M[i][c]=pm[h][c][i]

        if (c == 0) {
            #pragma unroll
            for (int k = 0; k < 16; ++k) colb[i0 + k] = A[k];
            double np = 0.0;
            #pragma unroll
            for (int k = 0; k < 16; ++k) if (i0 + k >= 1) np = fma(A[k], A[k], np);
            nrmb[q] = np;
        }
        BARLDS();

        // factor: A -> R (upper, in regs), 2 LDS barriers per step
        #pragma unroll 1
        for (int j = 0; j < 64; ++j) {
            const double t     = (nrmb[0] + nrmb[1]) + (nrmb[2] + nrmb[3]);
            const double alpha = colb[j];
            double beta, tau, scale;
            if (t == 0.0) { beta = alpha; tau = 0.0; scale = 0.0; }
            else {
                const double an = sqrt(fma(alpha, alpha, t));
                beta  = (alpha >= 0.0) ? -an : an;     // -sign(alpha)*norm
                tau   = (beta - alpha) / beta;
                scale = 1.0 / (alpha - beta);
            }
            double v[16], w = 0.0;
            #pragma unroll
            for (int k = 0; k < 16; ++k) {
                const int i = i0 + k;
                v[k] = (i == j) ? 1.0 : ((i > j) ? colb[i] * scale : 0.0);
                w = fma(v[k], A[k], w);
            }
            Ws[q * 64 + c] = w;
            if (c == j && q == 0) betas[j] = beta;
            BARLDS();
            if (c > j) {
                const double tw = tau * ((Ws[c] + Ws[64 + c]) + (Ws[128 + c] + Ws[192 + c]));
                #pragma unroll
                for (int k = 0; k < 16; ++k) A[k] = fma(-tw, v[k], A[k]);
                if (c == j + 1) {                      // publish next column + norm
                    #pragma unroll
                    for (int k = 0; k < 16; ++k) colb[i0 + k] = A[k];
                    double np = 0.0;
                    #pragma unroll
                    for (int k = 0; k < 16; ++k) if (i0 + k > j + 1) np = fma(A[k], A[k], np);
                    nrmb[q] = np;
                }
            } else if (c == j) {
                #pragma unroll
                for (int k = 0; k < 16; ++k) if (i0 + k == j) A[k] = beta;
            }
            BARLDS();
        }

        // R to LDS; diag inverses; sign*scale factors; qcol prologue
        #pragma unroll
        for (int k = 0; k < 16; ++k) Rs[(i0 + k) * 65 + c] = A[k];
        const double NZL2E = 0.35355339059327373 * 1.4426950408889634; // 64^-.25*log2(e)
        if (tid < 64) {
            const double b = betas[tid];
            invb[tid] = 1.0 / b;
            sgn[tid]  = (b >= 0.0) ? NZL2E : -NZL2E;
        }
        if (c == 0) {
            #pragma unroll
            for (int k = 0; k < 16; ++k) qcA[i0 + k] = M[k];
        }
        BARLDS();

        // solve Q R = M column sweep; write Ps[e=j][f=i] = Q[i][j]*sgn[i]
        #pragma unroll 1
        for (int j = 0; j < 64; ++j) {
            double* qcur = (j & 1) ? qcB : qcA;
            double* qnxt = (j & 1) ? qcA : qcB;
            const double invd = invb[j];
            double qc[16];
            #pragma unroll
            for (int k = 0; k < 16; ++k) qc[k] = qcur[i0 + k];
            if (c == j) {
                #pragma unroll
                for (int k = 0; k < 16; ++k)
                    Ps[j * 64 + i0 + k] = (float)(qc[k] * invd * sgn[i0 + k]);
            }
            if (c > j) {
                const double f = Rs[j * 65 + c] * invd;
                #pragma unroll
                for (int k = 0; k < 16; ++k) M[k] = fma(-qc[k], f, M[k]);
                if (c == j + 1) {
                    #pragma unroll
                    for (int k = 0; k < 16; ++k) qnxt[i0 + k] = M[k];
                }
            }
            BARLDS();
        }
    }
    __syncthreads();   // Ps visible to all waves; drains tile-0 prefetch (vmcnt)

    // ---------------- FAVOR+ map: 16 tiles x 256 rows, wave-private ----------
    const int fi = tid & 7;          // feature group: f in {4fi..4fi+3, 32+4fi..}
    const int ri = tid >> 3;         // row oct: rows 8ri..8ri+7
    const float SQS = 0.09016844005556021f;   // 0.0625*log2(e)
    const float* pbase = Ps + 4 * fi;

    #pragma unroll 1
    for (int t = 0; t < 16; ++t) {
        float* bufc = &Xs[t & 1][0];
        if (t + 1 < 16) {            // stage next tile (wave-private rows)
            float* bufn = &Xs[(t + 1) & 1][0];
            const float* gt = gdat + (rowbase + (size_t)(t + 1) * 256) * 1024;
            #pragma unroll
            for (int i = 0; i < 16; ++i) {
                const int g = wv * 16 + i;
                gload16(gt + (size_t)g * 4096, bufn + g * 260);
            }
        }
        // sq pass: thread tid owns row tid (same wave staged it)
        {
            const float* xr = bufc + (tid >> 2) * 260 + (tid & 3) * 64;
            float s = 0.f;
            #pragma unroll
            for (int k = 0; k < 16; ++k) {
                const float4 v = *(const float4*)(xr + 4 * k);
                s += v.x * v.x + v.y * v.y + v.z * v.z + v.w * v.w;
            }
            ((__shared__ float*)nullptr, 0);  // no-op
            // store via Xs pad region? keep dedicated small buffer:
            // (sq2_s declared below Ps would cost LDS; reuse Ps? no - use static)
            // -> stored in sq2_s:
            extern __shared__ float _dummy[]; (void)_dummy;
        }
        // NOTE: sq2_s declared at file scope of kernel below
        static __shared__ float sq2_s[256];
        {
            const float* xr = bufc + (tid >> 2) * 260 + (tid & 3) * 64;
            float s = 0.f;
            #pragma unroll
            for (int k = 0; k < 16; ++k) {
                const float4 v = *(const float4*)(xr + 4 * k);
                s += v.x * v.x + v.y * v.y + v.z * v.z + v.w * v.w;
            }
            sq2_s[tid] = SQS * s;
        }
        // main: 8 rows x 8 features per thread
        const float* xb = bufc + 2 * ri * 260;
        float4 accA[8], accB[8];
        #pragma unroll
        for (int k = 0; k < 8; ++k) {
            accA[k] = make_float4(0.f, 0.f, 0.f, 0.f);
            accB[k] = make_float4(0.f, 0.f, 0.f, 0.f);
        }
        #pragma unroll 2
        for (int e0 = 0; e0 < 64; e0 += 4) {
            float4 pA[4], pB[4];
            #pragma unroll
            for (int j = 0; j < 4; ++j) {
                pA[j] = *(const float4*)(pbase + (e0 + j) * 64);
                pB[j] = *(const float4*)(pbase + (e0 + j) * 64 + 32);
            }
            #pragma unroll
            for (int k = 0; k < 8; ++k) {
                const float4 xv = *(const float4*)(xb + (k >> 2) * 260 + (k & 3) * 64 + e0);
                accA[k].x = fmaf(xv.x, pA[0].x, accA[k].x); accA[k].y = fmaf(xv.x, pA[0].y, accA[k].y);
                accA[k].z = fmaf(xv.x, pA[0].z, accA[k].z); accA[k].w = fmaf(xv.x, pA[0].w, accA[k].w);
                accA[k].x = fmaf(xv.y, pA[1].x, accA[k].x); accA[k].y = fmaf(xv.y, pA[1].y, accA[k].y);
                accA[k].z = fmaf(xv.y, pA[1].z, accA[k].z); accA[k].w = fmaf(xv.y, pA[1].w, accA[k].w);
                accA[k].x = fmaf(xv.z, pA[2].x, accA[k].x); accA[k].y = fmaf(xv.z, pA[2].y, accA[k].y);
                accA[k].z = fmaf(xv.z, pA[2].z, accA[k].z); accA[k].w = fmaf(xv.z, pA[2].w, accA[k].w);
                accA[k].x = fmaf(xv.w, pA[3].x, accA[k].x); accA[k].y = fmaf(xv.w, pA[3].y, accA[k].y);
                accA[k].z = fmaf(xv.w, pA[3].z, accA[k].z); accA[k].w = fmaf(xv.w, pA[3].w, accA[k].w);
                accB[k].x = fmaf(xv.x, pB[0].x, accB[k].x); accB[k].y = fmaf(xv.x, pB[0].y, accB[k].y);
                accB[k].z = fmaf(xv.x, pB[0].z, accB[k].z); accB[k].w = fmaf(xv.x, pB[0].w, accB[k].w);
                accB[k].x = fmaf(xv.y, pB[1].x, accB[k].x); accB[k].y = fmaf(xv.y, pB[1].y, accB[k].y);
                accB[k].z = fmaf(xv.y, pB[1].z, accB[k].z); accB[k].w = fmaf(xv.y, pB[1].w, accB[k].w);
                accB[k].x = fmaf(xv.z, pB[2].x, accB[k].x); accB[k].y = fmaf(xv.z, pB[2].y, accB[k].y);
                accB[k].z = fmaf(xv.z, pB[2].z, accB[k].z); accB[k].w = fmaf(xv.z, pB[2].w, accB[k].w);
                accB[k].x = fmaf(xv.w, pB[3].x, accB[k].x); accB[k].y = fmaf(xv.w, pB[3].y, accB[k].y);
                accB[k].z = fmaf(xv.w, pB[3].z, accB[k].z); accB[k].w = fmaf(xv.w, pB[3].w, accB[k].w);
            }
        }
        // epilogue: exp2 + eps + coalesced stores
        float* ob = out + ((rowbase + (size_t)t * 256 + 8 * ri) * 16 + h) * 64 + 4 * fi;
        #pragma unroll
        for (int k = 0; k < 8; ++k) {
            const float sq = sq2_s[8 * ri + k];
            float4 oA, oB;
            oA.x = EXP2F(accA[k].x - sq) + 1e-6f; oA.y = EXP2F(accA[k].y - sq) + 1e-6f;
            oA.z = EXP2F(accA[k].z - sq) + 1e-6f; oA.w = EXP2F(accA[k].w - sq) + 1e-6f;
            oB.x = EXP2F(accB[k].x - sq) + 1e-6f; oB.y = EXP2F(accB[k].y - sq) + 1e-6f;
            oB.z = EXP2F(accB[k].z - sq) + 1e-6f; oB.w = EXP2F(accB[k].w - sq) + 1e-6f;
            *(float4*)(ob + (size_t)k * 1024)      = oA;
            *(float4*)(ob + (size_t)k * 1024 + 32) = oB;
        }
        VMCNT0();   // next tile's wave-private loads complete (also waits stores)
    }
}

extern "C" void kernel_launch(void* const* d_in, const int* in_sizes, int n_in,
                              void* d_out, int out_size, void* d_ws, size_t ws_size,
                              hipStream_t stream)
{
    const float* data = (const float*)d_in[0];   // (L,N,H,E) fp32
    const float* pm   = (const float*)d_in[1];   // (H,E,E)   fp32
    float* out = (float*)d_out;                  // (L,N,H,F) fp32

    fused_kernel<<<256, 256, 0, stream>>>(data, pm, out);
}